// Round 7
// baseline (817.551 us; speedup 1.0000x reference)
//
#include <hip/hip_runtime.h>
#include <math.h>

typedef float f32x2 __attribute__((ext_vector_type(2)));

// gelu exact-form via A&S 7.1.26 erf (|eps|<=1.5e-7); rcp/exp2 single-instr.
__device__ __forceinline__ float gelu(float x) {
    float z  = x * 0.70710678118654752f;
    float az = fabsf(z);
    float t  = __builtin_amdgcn_rcpf(fmaf(0.3275911f, az, 1.0f));
    float poly = fmaf(fmaf(fmaf(fmaf(1.061405429f, t, -1.453152027f), t,
                       1.421413741f), t, -0.284496736f), t, 0.254829592f);
    float e  = __builtin_amdgcn_exp2f(az * az * -1.4426950408889634f);
    float erfa = fmaf(-poly * t, e, 1.0f);
    float erfz = copysignf(erfa, z);
    return 0.5f * x * (1.0f + erfz);
}

// One MLP layer, pure fp32: out[n] = gelu(bias[n] + sum_k h[k]*W[k][n]).
// h lives in this thread's private LDS row (runtime k index OK in LDS);
// acc kept as f32x2[32] registers (static index) -> v_pk_fma_f32;
// W row address is wave-uniform -> scalar s_load broadcast.
template <int K>
__device__ __forceinline__ void mlp_layer(float* hrow,
                                          const float* __restrict__ W,
                                          const float* __restrict__ bias) {
    f32x2 acc[32];
    #pragma unroll
    for (int m = 0; m < 32; ++m)
        acc[m] = *(const f32x2*)(bias + 2 * m);
    #pragma clang loop unroll_count(2)
    for (int k = 0; k < K; ++k) {
        const float hk = hrow[k];
        const f32x2 hk2 = { hk, hk };
        const f32x2* wr = (const f32x2*)(W + k * 64);
        #pragma unroll
        for (int m = 0; m < 32; ++m)
            acc[m] = __builtin_elementwise_fma(hk2, wr[m], acc[m]);
    }
    #pragma unroll
    for (int m = 0; m < 32; ++m) {
        f32x2 g = { gelu(acc[m][0]), gelu(acc[m][1]) };
        *(f32x2*)(hrow + 2 * m) = g;   // ds_write_b64
    }
}

// ---------- single kernel: features + polar + fp32 MLP + epilogue ----------
// No prep kernel, no workspace, no barriers, no cross-thread traffic.
__global__ void __launch_bounds__(128) stress_main(
    const float* __restrict__ F, const float* __restrict__ Cin,
    const float* __restrict__ trajw, const int* __restrict__ traj_ids,
    const float* __restrict__ w1, const float* __restrict__ b1,
    const float* __restrict__ w2, const float* __restrict__ b2,
    const float* __restrict__ w3, const float* __restrict__ b3,
    const float* __restrict__ w4, const float* __restrict__ b4,
    const float* __restrict__ w5, const float* __restrict__ b5,
    float* __restrict__ out, int Btotal)
{
    __shared__ float hbuf[128 * 65];              // 33,280 B; stride 65 -> 2-way banks (free)
    const int t = threadIdx.x;
    const int b = blockIdx.x * 128 + t;
    if (b >= Btotal) return;                      // no barriers anywhere: safe
    float* hrow = &hbuf[t * 65];

    // ================= prologue: features + polar decomposition ============
    float f[9];
    float fv[57];
    const float* Fp = F + b * 9;
    #pragma unroll
    for (int i = 0; i < 9; ++i) f[i] = Fp[i];
    const float* Cp = Cin + b * 9;
    #pragma unroll
    for (int i = 0; i < 9; ++i) fv[16 + i] = Cp[i];
    const int tid0 = traj_ids[0];
    const float* lp = trajw + tid0 * 32;
    #pragma unroll
    for (int e = 0; e < 32; ++e) fv[25 + e] = lp[e];

    float s00 = fmaf(f[0], f[0], fmaf(f[3], f[3], f[6] * f[6]));
    float s01 = fmaf(f[0], f[1], fmaf(f[3], f[4], f[6] * f[7]));
    float s02 = fmaf(f[0], f[2], fmaf(f[3], f[5], f[6] * f[8]));
    float s11 = fmaf(f[1], f[1], fmaf(f[4], f[4], f[7] * f[7]));
    float s12 = fmaf(f[1], f[2], fmaf(f[4], f[5], f[7] * f[8]));
    float s22 = fmaf(f[2], f[2], fmaf(f[5], f[5], f[8] * f[8]));
    fv[3] = s00; fv[4] = s01; fv[5] = s02;
    fv[6] = s01; fv[7] = s11; fv[8] = s12;
    fv[9] = s02; fv[10] = s12; fv[11] = s22;

    float det = f[0] * (f[4] * f[8] - f[5] * f[7])
              - f[1] * (f[3] * f[8] - f[5] * f[6])
              + f[2] * (f[3] * f[7] - f[4] * f[6]);
    float detc = det < 0.0f ? 1e-9f : det;
    fv[12] = detc;
    fv[13] = __builtin_amdgcn_logf(detc) * 0.6931471805599453f;
    float f00c = fmaxf(f[0], 1e-6f);
    fv[14] = f00c;
    fv[15] = __builtin_amdgcn_logf(f00c) * 0.6931471805599453f;

    // Jacobi eigendecomposition of FtF (round-1/2-verified algorithm)
    float a00 = s00, a01 = s01, a02 = s02, a11 = s11, a12 = s12, a22 = s22;
    float v00 = 1.f, v01 = 0.f, v02 = 0.f;
    float v10 = 0.f, v11 = 1.f, v12 = 0.f;
    float v20 = 0.f, v21 = 0.f, v22 = 1.f;
    auto rot = [](float& app, float& aqq, float& apq, float& arp, float& arq,
                  float& Vp0, float& Vq0, float& Vp1, float& Vq1, float& Vp2, float& Vq2) {
        float pq = apq;
        if (fabsf(pq) > 1e-20f) {
            float tau = (aqq - app) * 0.5f * __builtin_amdgcn_rcpf(pq);
            float tt = copysignf(__builtin_amdgcn_rcpf(
                           fabsf(tau) + __builtin_amdgcn_sqrtf(fmaf(tau, tau, 1.0f))), tau);
            float cc = __builtin_amdgcn_rsqf(fmaf(tt, tt, 1.0f));
            float ss = tt * cc;
            app = app - tt * pq;  aqq = aqq + tt * pq;  apq = 0.0f;
            float rp = arp, rq = arq;
            arp = cc * rp - ss * rq;  arq = ss * rp + cc * rq;
            float x0 = Vp0, y0 = Vq0; Vp0 = cc * x0 - ss * y0; Vq0 = ss * x0 + cc * y0;
            float x1 = Vp1, y1 = Vq1; Vp1 = cc * x1 - ss * y1; Vq1 = ss * x1 + cc * y1;
            float x2 = Vp2, y2 = Vq2; Vp2 = cc * x2 - ss * y2; Vq2 = ss * x2 + cc * y2;
        }
    };
    #pragma unroll
    for (int sweep = 0; sweep < 4; ++sweep) {
        rot(a00, a11, a01, a02, a12, v00, v01, v10, v11, v20, v21);
        rot(a00, a22, a02, a01, a12, v00, v02, v10, v12, v20, v22);
        rot(a11, a22, a12, a01, a02, v01, v02, v11, v12, v21, v22);
    }
    #define CSWAP(La, Lb, pA0, pB0, pA1, pB1, pA2, pB2)                     \
        if (La < Lb) { float t_;                                            \
            t_ = La; La = Lb; Lb = t_;   t_ = pA0; pA0 = pB0; pB0 = t_;     \
            t_ = pA1; pA1 = pB1; pB1 = t_; t_ = pA2; pA2 = pB2; pB2 = t_; }
    CSWAP(a00, a11, v00, v01, v10, v11, v20, v21)
    CSWAP(a00, a22, v00, v02, v10, v12, v20, v22)
    CSWAP(a11, a22, v01, v02, v11, v12, v21, v22)
    #undef CSWAP

    float sg0 = __builtin_amdgcn_sqrtf(fmaxf(a00, 0.0f));
    float sg1 = __builtin_amdgcn_sqrtf(fmaxf(a11, 0.0f));
    float sg2 = __builtin_amdgcn_sqrtf(fmaxf(a22, 0.0f));
    fv[0] = sg0; fv[1] = sg1; fv[2] = sg2;

    float i0 = __builtin_amdgcn_rcpf(fmaxf(sg0, 1e-12f));
    float i1 = __builtin_amdgcn_rcpf(fmaxf(sg1, 1e-12f));
    float i2 = __builtin_amdgcn_rcpf(fmaxf(sg2, 1e-12f));
    float A00 = i0*v00*v00 + i1*v01*v01 + i2*v02*v02;
    float A01 = i0*v00*v10 + i1*v01*v11 + i2*v02*v12;
    float A02 = i0*v00*v20 + i1*v01*v21 + i2*v02*v22;
    float A11 = i0*v10*v10 + i1*v11*v11 + i2*v12*v12;
    float A12 = i0*v10*v20 + i1*v11*v21 + i2*v12*v22;
    float A22 = i0*v20*v20 + i1*v21*v21 + i2*v22*v22;
    float R00 = f[0]*A00 + f[1]*A01 + f[2]*A02;
    float R01 = f[0]*A01 + f[1]*A11 + f[2]*A12;
    float R02 = f[0]*A02 + f[1]*A12 + f[2]*A22;
    float R10 = f[3]*A00 + f[4]*A01 + f[5]*A02;
    float R11 = f[3]*A01 + f[4]*A11 + f[5]*A12;
    float R12 = f[3]*A02 + f[4]*A12 + f[5]*A22;
    float R20 = f[6]*A00 + f[7]*A01 + f[8]*A02;
    float R21 = f[6]*A01 + f[7]*A11 + f[8]*A12;
    float R22 = f[6]*A02 + f[7]*A12 + f[8]*A22;

    // features -> this thread's LDS row (56 as pairs, then the odd one)
    #pragma unroll
    for (int i = 0; i < 28; ++i) {
        f32x2 p = { fv[2 * i], fv[2 * i + 1] };
        *(f32x2*)(hrow + 2 * i) = p;
    }
    hrow[56] = fv[56];

    // ================= MLP: 4 x (64->64, gelu) + head, all fp32 ============
    mlp_layer<57>(hrow, w1, b1);
    mlp_layer<64>(hrow, w2, b2);
    mlp_layer<64>(hrow, w3, b3);
    mlp_layer<64>(hrow, w4, b4);

    float o[9];
    #pragma unroll
    for (int n = 0; n < 9; ++n) o[n] = b5[n];
    #pragma clang loop unroll_count(2)
    for (int k = 0; k < 64; ++k) {
        const float hk = hrow[k];
        const float* wr = w5 + k * 9;
        #pragma unroll
        for (int n = 0; n < 9; ++n) o[n] = fmaf(hk, wr[n], o[n]);
    }

    // ================= epilogue: symmetrize, P = R*xs, cauchy = P*F^T ======
    float xs00 = o[0];
    float xs01 = 0.5f * (o[1] + o[3]);
    float xs02 = 0.5f * (o[2] + o[6]);
    float xs11 = o[4];
    float xs12 = 0.5f * (o[5] + o[7]);
    float xs22 = o[8];

    float P00 = R00*xs00 + R01*xs01 + R02*xs02;
    float P01 = R00*xs01 + R01*xs11 + R02*xs12;
    float P02 = R00*xs02 + R01*xs12 + R02*xs22;
    float P10 = R10*xs00 + R11*xs01 + R12*xs02;
    float P11 = R10*xs01 + R11*xs11 + R12*xs12;
    float P12 = R10*xs02 + R11*xs12 + R12*xs22;
    float P20 = R20*xs00 + R21*xs01 + R22*xs02;
    float P21 = R20*xs01 + R21*xs11 + R22*xs12;
    float P22 = R20*xs02 + R21*xs12 + R22*xs22;

    // cauchy[i][j] = sum_k P[i][k] * F[j][k]
    // NOTE: op[7] = P20*f[3] + P21*f[4] + P22*f[5] (f[5], not f[7]).
    float* op = out + b * 9;
    op[0] = P00*f[0] + P01*f[1] + P02*f[2];
    op[1] = P00*f[3] + P01*f[4] + P02*f[5];
    op[2] = P00*f[6] + P01*f[7] + P02*f[8];
    op[3] = P10*f[0] + P11*f[1] + P12*f[2];
    op[4] = P10*f[3] + P11*f[4] + P12*f[5];
    op[5] = P10*f[6] + P11*f[7] + P12*f[8];
    op[6] = P20*f[0] + P21*f[1] + P22*f[2];
    op[7] = P20*f[3] + P21*f[4] + P22*f[5];
    op[8] = P20*f[6] + P21*f[7] + P22*f[8];
}

extern "C" void kernel_launch(void* const* d_in, const int* in_sizes, int n_in,
                              void* d_out, int out_size, void* d_ws, size_t ws_size,
                              hipStream_t stream) {
    const float* F     = (const float*)d_in[0];
    const float* C     = (const float*)d_in[1];
    const float* w1    = (const float*)d_in[2];
    const float* b1    = (const float*)d_in[3];
    const float* w2    = (const float*)d_in[4];
    const float* b2    = (const float*)d_in[5];
    const float* w3    = (const float*)d_in[6];
    const float* b3    = (const float*)d_in[7];
    const float* w4    = (const float*)d_in[8];
    const float* b4    = (const float*)d_in[9];
    const float* w5    = (const float*)d_in[10];
    const float* b5    = (const float*)d_in[11];
    const float* trajw = (const float*)d_in[12];
    const int*   tids  = (const int*)d_in[13];
    float* out = (float*)d_out;
    (void)d_ws; (void)ws_size;

    int B = in_sizes[0] / 9;
    int grid = (B + 127) / 128;
    stress_main<<<grid, 128, 0, stream>>>(F, C, trajw, tids,
                                          w1, b1, w2, b2, w3, b3, w4, b4, w5, b5,
                                          out, B);
}

// Round 8
// 729.082 us; speedup vs baseline: 1.1213x; 1.1213x over previous
//
#include <hip/hip_runtime.h>
#include <math.h>

typedef float f32x2 __attribute__((ext_vector_type(2)));
typedef float f32x4 __attribute__((ext_vector_type(4)));

// gelu exact-form via A&S 7.1.26 erf (|eps|<=1.5e-7); rcp/exp2 single-instr.
__device__ __forceinline__ float gelu(float x) {
    float z  = x * 0.70710678118654752f;
    float az = fabsf(z);
    float t  = __builtin_amdgcn_rcpf(fmaf(0.3275911f, az, 1.0f));
    float poly = fmaf(fmaf(fmaf(fmaf(1.061405429f, t, -1.453152027f), t,
                       1.421413741f), t, -0.284496736f), t, 0.254829592f);
    float e  = __builtin_amdgcn_exp2f(az * az * -1.4426950408889634f);
    float erfa = fmaf(-poly * t, e, 1.0f);
    float erfz = copysignf(erfa, z);
    return 0.5f * x * (1.0f + erfz);
}

// Per-thread h row: 64 floats at hb + t*64, stored in 16B units with XOR
// swizzle u' = u ^ (t&15). Stride-64 rows alone would be 64-way bank
// conflicted; the swizzle spreads the 64 lanes' b128 accesses evenly
// (8 accesses/bank = the hardware minimum for b128 x 64 lanes).
__device__ __forceinline__ float* hunit(float* hb, int t, int u) {
    return hb + t * 64 + ((u ^ (t & 15)) << 2);
}

// One MLP layer, pure fp32: out[n] = gelu(bias[n] + sum_k h[k]*W[k][n]).
// h read as f32x4 units (1 ds_read_b128 per 4 k -> latency fully hidden
// under 256 cycles of pk_fma); acc as f32x2[32] regs -> v_pk_fma_f32;
// W row address wave-uniform -> scalar loads broadcast.
template <int K>
__device__ __forceinline__ void mlp_layer(float* hb, int t,
                                          const float* __restrict__ W,
                                          const float* __restrict__ bias) {
    f32x2 acc[32];
    #pragma unroll
    for (int m = 0; m < 32; ++m)
        acc[m] = *(const f32x2*)(bias + 2 * m);

    constexpr int NU = K >> 2;          // full 4-k units
    #pragma clang loop unroll_count(2)
    for (int u = 0; u < NU; ++u) {
        f32x4 hv = *(const f32x4*)hunit(hb, t, u);
        #pragma unroll
        for (int j = 0; j < 4; ++j) {
            const float hk = hv[j];
            const f32x2 hk2 = { hk, hk };
            const f32x2* wr = (const f32x2*)(W + (u * 4 + j) * 64);
            #pragma unroll
            for (int m = 0; m < 32; ++m)
                acc[m] = __builtin_elementwise_fma(hk2, wr[m], acc[m]);
        }
    }
    if constexpr ((K & 3) != 0) {       // tail unit (K=57: k=56 only)
        f32x4 hv = *(const f32x4*)hunit(hb, t, NU);
        #pragma unroll
        for (int j = 0; j < (K & 3); ++j) {
            const float hk = hv[j];
            const f32x2 hk2 = { hk, hk };
            const f32x2* wr = (const f32x2*)(W + (NU * 4 + j) * 64);
            #pragma unroll
            for (int m = 0; m < 32; ++m)
                acc[m] = __builtin_elementwise_fma(hk2, wr[m], acc[m]);
        }
    }

    // gelu + write back (reads of this row all complete above; same thread)
    #pragma unroll
    for (int u = 0; u < 16; ++u) {
        f32x4 g;
        g[0] = gelu(acc[2 * u][0]);     g[1] = gelu(acc[2 * u][1]);
        g[2] = gelu(acc[2 * u + 1][0]); g[3] = gelu(acc[2 * u + 1][1]);
        *(f32x4*)hunit(hb, t, u) = g;
    }
}

// ---------- single kernel: features + polar + fp32 MLP + epilogue ----------
// No prep kernel, no workspace, no barriers, no cross-thread traffic.
__global__ void __launch_bounds__(128) stress_main(
    const float* __restrict__ F, const float* __restrict__ Cin,
    const float* __restrict__ trajw, const int* __restrict__ traj_ids,
    const float* __restrict__ w1, const float* __restrict__ b1,
    const float* __restrict__ w2, const float* __restrict__ b2,
    const float* __restrict__ w3, const float* __restrict__ b3,
    const float* __restrict__ w4, const float* __restrict__ b4,
    const float* __restrict__ w5, const float* __restrict__ b5,
    float* __restrict__ out, int Btotal)
{
    __shared__ float hbuf[128 * 64];              // 32,768 B -> 5 blocks/CU (163,840 = 160 KiB exactly)
    const int t = threadIdx.x;
    const int b = blockIdx.x * 128 + t;
    if (b >= Btotal) return;                      // no barriers anywhere: safe

    // ================= prologue: features + polar decomposition ============
    float f[9];
    float fv[64];
    #pragma unroll
    for (int i = 57; i < 64; ++i) fv[i] = 0.0f;   // pad so unit writes are full
    const float* Fp = F + b * 9;
    #pragma unroll
    for (int i = 0; i < 9; ++i) f[i] = Fp[i];
    const float* Cp = Cin + b * 9;
    #pragma unroll
    for (int i = 0; i < 9; ++i) fv[16 + i] = Cp[i];
    const int tid0 = traj_ids[0];
    const float* lp = trajw + tid0 * 32;
    #pragma unroll
    for (int e = 0; e < 32; ++e) fv[25 + e] = lp[e];

    float s00 = fmaf(f[0], f[0], fmaf(f[3], f[3], f[6] * f[6]));
    float s01 = fmaf(f[0], f[1], fmaf(f[3], f[4], f[6] * f[7]));
    float s02 = fmaf(f[0], f[2], fmaf(f[3], f[5], f[6] * f[8]));
    float s11 = fmaf(f[1], f[1], fmaf(f[4], f[4], f[7] * f[7]));
    float s12 = fmaf(f[1], f[2], fmaf(f[4], f[5], f[7] * f[8]));
    float s22 = fmaf(f[2], f[2], fmaf(f[5], f[5], f[8] * f[8]));
    fv[3] = s00; fv[4] = s01; fv[5] = s02;
    fv[6] = s01; fv[7] = s11; fv[8] = s12;
    fv[9] = s02; fv[10] = s12; fv[11] = s22;

    float det = f[0] * (f[4] * f[8] - f[5] * f[7])
              - f[1] * (f[3] * f[8] - f[5] * f[6])
              + f[2] * (f[3] * f[7] - f[4] * f[6]);
    float detc = det < 0.0f ? 1e-9f : det;
    fv[12] = detc;
    fv[13] = __builtin_amdgcn_logf(detc) * 0.6931471805599453f;
    float f00c = fmaxf(f[0], 1e-6f);
    fv[14] = f00c;
    fv[15] = __builtin_amdgcn_logf(f00c) * 0.6931471805599453f;

    // Jacobi eigendecomposition of FtF (round-1/2-verified algorithm)
    float a00 = s00, a01 = s01, a02 = s02, a11 = s11, a12 = s12, a22 = s22;
    float v00 = 1.f, v01 = 0.f, v02 = 0.f;
    float v10 = 0.f, v11 = 1.f, v12 = 0.f;
    float v20 = 0.f, v21 = 0.f, v22 = 1.f;
    auto rot = [](float& app, float& aqq, float& apq, float& arp, float& arq,
                  float& Vp0, float& Vq0, float& Vp1, float& Vq1, float& Vp2, float& Vq2) {
        float pq = apq;
        if (fabsf(pq) > 1e-20f) {
            float tau = (aqq - app) * 0.5f * __builtin_amdgcn_rcpf(pq);
            float tt = copysignf(__builtin_amdgcn_rcpf(
                           fabsf(tau) + __builtin_amdgcn_sqrtf(fmaf(tau, tau, 1.0f))), tau);
            float cc = __builtin_amdgcn_rsqf(fmaf(tt, tt, 1.0f));
            float ss = tt * cc;
            app = app - tt * pq;  aqq = aqq + tt * pq;  apq = 0.0f;
            float rp = arp, rq = arq;
            arp = cc * rp - ss * rq;  arq = ss * rp + cc * rq;
            float x0 = Vp0, y0 = Vq0; Vp0 = cc * x0 - ss * y0; Vq0 = ss * x0 + cc * y0;
            float x1 = Vp1, y1 = Vq1; Vp1 = cc * x1 - ss * y1; Vq1 = ss * x1 + cc * y1;
            float x2 = Vp2, y2 = Vq2; Vp2 = cc * x2 - ss * y2; Vq2 = ss * x2 + cc * y2;
        }
    };
    #pragma unroll
    for (int sweep = 0; sweep < 4; ++sweep) {
        rot(a00, a11, a01, a02, a12, v00, v01, v10, v11, v20, v21);
        rot(a00, a22, a02, a01, a12, v00, v02, v10, v12, v20, v22);
        rot(a11, a22, a12, a01, a02, v01, v02, v11, v12, v21, v22);
    }
    #define CSWAP(La, Lb, pA0, pB0, pA1, pB1, pA2, pB2)                     \
        if (La < Lb) { float t_;                                            \
            t_ = La; La = Lb; Lb = t_;   t_ = pA0; pA0 = pB0; pB0 = t_;     \
            t_ = pA1; pA1 = pB1; pB1 = t_; t_ = pA2; pA2 = pB2; pB2 = t_; }
    CSWAP(a00, a11, v00, v01, v10, v11, v20, v21)
    CSWAP(a00, a22, v00, v02, v10, v12, v20, v22)
    CSWAP(a11, a22, v01, v02, v11, v12, v21, v22)
    #undef CSWAP

    float sg0 = __builtin_amdgcn_sqrtf(fmaxf(a00, 0.0f));
    float sg1 = __builtin_amdgcn_sqrtf(fmaxf(a11, 0.0f));
    float sg2 = __builtin_amdgcn_sqrtf(fmaxf(a22, 0.0f));
    fv[0] = sg0; fv[1] = sg1; fv[2] = sg2;

    float i0 = __builtin_amdgcn_rcpf(fmaxf(sg0, 1e-12f));
    float i1 = __builtin_amdgcn_rcpf(fmaxf(sg1, 1e-12f));
    float i2 = __builtin_amdgcn_rcpf(fmaxf(sg2, 1e-12f));
    float A00 = i0*v00*v00 + i1*v01*v01 + i2*v02*v02;
    float A01 = i0*v00*v10 + i1*v01*v11 + i2*v02*v12;
    float A02 = i0*v00*v20 + i1*v01*v21 + i2*v02*v22;
    float A11 = i0*v10*v10 + i1*v11*v11 + i2*v12*v12;
    float A12 = i0*v10*v20 + i1*v11*v21 + i2*v12*v22;
    float A22 = i0*v20*v20 + i1*v21*v21 + i2*v22*v22;
    float R00 = f[0]*A00 + f[1]*A01 + f[2]*A02;
    float R01 = f[0]*A01 + f[1]*A11 + f[2]*A12;
    float R02 = f[0]*A02 + f[1]*A12 + f[2]*A22;
    float R10 = f[3]*A00 + f[4]*A01 + f[5]*A02;
    float R11 = f[3]*A01 + f[4]*A11 + f[5]*A12;
    float R12 = f[3]*A02 + f[4]*A12 + f[5]*A22;
    float R20 = f[6]*A00 + f[7]*A01 + f[8]*A02;
    float R21 = f[6]*A01 + f[7]*A11 + f[8]*A12;
    float R22 = f[6]*A02 + f[7]*A12 + f[8]*A22;

    // features -> this thread's swizzled LDS row (16 x ds_write_b128)
    #pragma unroll
    for (int u = 0; u < 16; ++u) {
        f32x4 p = { fv[4*u], fv[4*u+1], fv[4*u+2], fv[4*u+3] };
        *(f32x4*)hunit(hbuf, t, u) = p;
    }

    // ================= MLP: 4 x (64->64, gelu) + head, all fp32 ============
    mlp_layer<57>(hbuf, t, w1, b1);
    mlp_layer<64>(hbuf, t, w2, b2);
    mlp_layer<64>(hbuf, t, w3, b3);
    mlp_layer<64>(hbuf, t, w4, b4);

    // head: 64 -> 9; out[0..7] packed as 4 pk_fma, out[8] scalar
    f32x2 o01 = { b5[0], b5[1] }, o23 = { b5[2], b5[3] };
    f32x2 o45 = { b5[4], b5[5] }, o67 = { b5[6], b5[7] };
    float o8 = b5[8];
    #pragma clang loop unroll_count(2)
    for (int u = 0; u < 16; ++u) {
        f32x4 hv = *(const f32x4*)hunit(hbuf, t, u);
        #pragma unroll
        for (int j = 0; j < 4; ++j) {
            const float hk = hv[j];
            const f32x2 hk2 = { hk, hk };
            const float* wr = w5 + (u * 4 + j) * 9;
            f32x2 w01 = { wr[0], wr[1] }, w23 = { wr[2], wr[3] };
            f32x2 w45 = { wr[4], wr[5] }, w67 = { wr[6], wr[7] };
            o01 = __builtin_elementwise_fma(hk2, w01, o01);
            o23 = __builtin_elementwise_fma(hk2, w23, o23);
            o45 = __builtin_elementwise_fma(hk2, w45, o45);
            o67 = __builtin_elementwise_fma(hk2, w67, o67);
            o8  = fmaf(hk, wr[8], o8);
        }
    }
    float o[9] = { o01[0], o01[1], o23[0], o23[1], o45[0], o45[1], o67[0], o67[1], o8 };

    // ================= epilogue: symmetrize, P = R*xs, cauchy = P*F^T ======
    float xs00 = o[0];
    float xs01 = 0.5f * (o[1] + o[3]);
    float xs02 = 0.5f * (o[2] + o[6]);
    float xs11 = o[4];
    float xs12 = 0.5f * (o[5] + o[7]);
    float xs22 = o[8];

    float P00 = R00*xs00 + R01*xs01 + R02*xs02;
    float P01 = R00*xs01 + R01*xs11 + R02*xs12;
    float P02 = R00*xs02 + R01*xs12 + R02*xs22;
    float P10 = R10*xs00 + R11*xs01 + R12*xs02;
    float P11 = R10*xs01 + R11*xs11 + R12*xs12;
    float P12 = R10*xs02 + R11*xs12 + R12*xs22;
    float P20 = R20*xs00 + R21*xs01 + R22*xs02;
    float P21 = R20*xs01 + R21*xs11 + R22*xs12;
    float P22 = R20*xs02 + R21*xs12 + R22*xs22;

    // cauchy[i][j] = sum_k P[i][k] * F[j][k]
    // NOTE: op[7] = P20*f[3] + P21*f[4] + P22*f[5] (f[5], not f[7]).
    float* op = out + b * 9;
    op[0] = P00*f[0] + P01*f[1] + P02*f[2];
    op[1] = P00*f[3] + P01*f[4] + P02*f[5];
    op[2] = P00*f[6] + P01*f[7] + P02*f[8];
    op[3] = P10*f[0] + P11*f[1] + P12*f[2];
    op[4] = P10*f[3] + P11*f[4] + P12*f[5];
    op[5] = P10*f[6] + P11*f[7] + P12*f[8];
    op[6] = P20*f[0] + P21*f[1] + P22*f[2];
    op[7] = P20*f[3] + P21*f[4] + P22*f[5];
    op[8] = P20*f[6] + P21*f[7] + P22*f[8];
}

extern "C" void kernel_launch(void* const* d_in, const int* in_sizes, int n_in,
                              void* d_out, int out_size, void* d_ws, size_t ws_size,
                              hipStream_t stream) {
    const float* F     = (const float*)d_in[0];
    const float* C     = (const float*)d_in[1];
    const float* w1    = (const float*)d_in[2];
    const float* b1    = (const float*)d_in[3];
    const float* w2    = (const float*)d_in[4];
    const float* b2    = (const float*)d_in[5];
    const float* w3    = (const float*)d_in[6];
    const float* b3    = (const float*)d_in[7];
    const float* w4    = (const float*)d_in[8];
    const float* b4    = (const float*)d_in[9];
    const float* w5    = (const float*)d_in[10];
    const float* b5    = (const float*)d_in[11];
    const float* trajw = (const float*)d_in[12];
    const int*   tids  = (const int*)d_in[13];
    float* out = (float*)d_out;
    (void)d_ws; (void)ws_size;

    int B = in_sizes[0] / 9;
    int grid = (B + 127) / 128;
    stress_main<<<grid, 128, 0, stream>>>(F, C, trajw, tids,
                                          w1, b1, w2, b2, w3, b3, w4, b4, w5, b5,
                                          out, B);
}

// Round 9
// 608.089 us; speedup vs baseline: 1.3445x; 1.1990x over previous
//
#include <hip/hip_runtime.h>
#include <math.h>

typedef float f32x2 __attribute__((ext_vector_type(2)));
typedef float f32x4 __attribute__((ext_vector_type(4)));

// gelu exact-form via A&S 7.1.26 erf (|eps|<=1.5e-7); rcp/exp2 single-instr.
__device__ __forceinline__ float gelu(float x) {
    float z  = x * 0.70710678118654752f;
    float az = fabsf(z);
    float t  = __builtin_amdgcn_rcpf(fmaf(0.3275911f, az, 1.0f));
    float poly = fmaf(fmaf(fmaf(fmaf(1.061405429f, t, -1.453152027f), t,
                       1.421413741f), t, -0.284496736f), t, 0.254829592f);
    float e  = __builtin_amdgcn_exp2f(az * az * -1.4426950408889634f);
    float erfa = fmaf(-poly * t, e, 1.0f);
    float erfz = copysignf(erfa, z);
    return 0.5f * x * (1.0f + erfz);
}

// h row: one per SAMPLE (64 fp32 = 16 x 16B units), shared by the block's two
// waves. Unit index XOR-swizzled by (sample&15): rows are 256B (bank-aligned),
// so unswizzled all lanes would hit one 4-bank group; the XOR spreads 64 lanes
// across 8 groups -> 8 accesses/bank = the b128 minimum (conflict-free).
__device__ __forceinline__ float* hu(float* hrow, int swz, int u) {
    return hrow + ((u ^ swz) << 2);
}

// One MLP layer: this thread computes out[n], n in [wvu*32, wvu*32+32), for
// its sample, summing over ALL k (reads the full row). Weight/bias addresses
// are wave-uniform (wvu from readfirstlane) -> scalar s_load broadcast.
// Cross-wave RAW/WAR on the row handled by the two barriers.
template <int NFULL, bool TAIL>
__device__ __forceinline__ void mlp_layer(float* hrow, int swz, int wvu,
                                          const float* __restrict__ W,
                                          const float* __restrict__ bias) {
    f32x2 acc[16];
    const float* bh = bias + wvu * 32;
    #pragma unroll
    for (int m = 0; m < 16; ++m)
        acc[m] = *(const f32x2*)(bh + 2 * m);

    #pragma clang loop unroll_count(2)
    for (int u = 0; u < NFULL; ++u) {
        f32x4 hv = *(const f32x4*)hu(hrow, swz, u);
        #pragma unroll
        for (int j = 0; j < 4; ++j) {
            const float hk = hv[j];
            const f32x2 hk2 = { hk, hk };
            const f32x2* wr = (const f32x2*)(W + (u * 4 + j) * 64 + wvu * 32);
            #pragma unroll
            for (int m = 0; m < 16; ++m)
                acc[m] = __builtin_elementwise_fma(hk2, wr[m], acc[m]);
        }
    }
    if constexpr (TAIL) {                 // layer 1: k = 56 only (57..63 zero)
        f32x4 hv = *(const f32x4*)hu(hrow, swz, NFULL);
        const f32x2 hk2 = { hv[0], hv[0] };
        const f32x2* wr = (const f32x2*)(W + (NFULL * 4) * 64 + wvu * 32);
        #pragma unroll
        for (int m = 0; m < 16; ++m)
            acc[m] = __builtin_elementwise_fma(hk2, wr[m], acc[m]);
    }

    __syncthreads();                      // all reads of old h done (block-wide)
    #pragma unroll
    for (int u = 0; u < 8; ++u) {
        f32x4 g;
        g[0] = gelu(acc[2 * u][0]);     g[1] = gelu(acc[2 * u][1]);
        g[2] = gelu(acc[2 * u + 1][0]); g[3] = gelu(acc[2 * u + 1][1]);
        *(f32x4*)hu(hrow, swz, wvu * 8 + u) = g;   // own n-half: units wv*8..+7
    }
    __syncthreads();                      // new h visible to both waves
}

// ---------- single kernel: features + polar + fp32 MLP + epilogue ----------
// Block = 128 threads = 2 waves over 64 samples; wave wv owns n-half wv.
// __launch_bounds__(128,4): 4 waves/EU -> VGPR capped at 128 -> with 16KB LDS
// per block, 8 blocks/CU = 16 waves/CU = 4 waves/SIMD (2x round-8 occupancy).
__global__ void __launch_bounds__(128, 4) stress_main(
    const float* __restrict__ F, const float* __restrict__ Cin,
    const float* __restrict__ trajw, const int* __restrict__ traj_ids,
    const float* __restrict__ w1, const float* __restrict__ b1,
    const float* __restrict__ w2, const float* __restrict__ b2,
    const float* __restrict__ w3, const float* __restrict__ b3,
    const float* __restrict__ w4, const float* __restrict__ b4,
    const float* __restrict__ w5, const float* __restrict__ b5,
    float* __restrict__ out, int Btotal)
{
    __shared__ float hbuf[64 * 64];               // 16,384 B
    const int t    = threadIdx.x;
    const int lane = t & 63;                      // sample within block
    const int wv   = t >> 6;                      // n-half
    const int wvu  = __builtin_amdgcn_readfirstlane(wv);  // force SGPR (scalar W loads)
    const int swz  = lane & 15;
    const int b    = blockIdx.x * 64 + lane;
    const bool live = (b < Btotal);
    float* hrow = hbuf + lane * 64;

    // ================= prologue: features + polar decomposition ============
    // Both waves compute the same sample's prologue (dup ~3% of work); each
    // writes its half of the feature row. No early returns (barriers below).
    float f[9];
    float fv[64];
    #pragma unroll
    for (int i = 57; i < 64; ++i) fv[i] = 0.0f;
    if (live) {
        const float* Fp = F + b * 9;
        #pragma unroll
        for (int i = 0; i < 9; ++i) f[i] = Fp[i];
        const float* Cp = Cin + b * 9;
        #pragma unroll
        for (int i = 0; i < 9; ++i) fv[16 + i] = Cp[i];
    } else {
        #pragma unroll
        for (int i = 0; i < 9; ++i) { f[i] = 0.0f; fv[16 + i] = 0.0f; }
    }
    const int tid0 = traj_ids[0];
    const float* lp = trajw + tid0 * 32;
    #pragma unroll
    for (int e = 0; e < 32; ++e) fv[25 + e] = lp[e];

    float s00 = fmaf(f[0], f[0], fmaf(f[3], f[3], f[6] * f[6]));
    float s01 = fmaf(f[0], f[1], fmaf(f[3], f[4], f[6] * f[7]));
    float s02 = fmaf(f[0], f[2], fmaf(f[3], f[5], f[6] * f[8]));
    float s11 = fmaf(f[1], f[1], fmaf(f[4], f[4], f[7] * f[7]));
    float s12 = fmaf(f[1], f[2], fmaf(f[4], f[5], f[7] * f[8]));
    float s22 = fmaf(f[2], f[2], fmaf(f[5], f[5], f[8] * f[8]));
    fv[3] = s00; fv[4] = s01; fv[5] = s02;
    fv[6] = s01; fv[7] = s11; fv[8] = s12;
    fv[9] = s02; fv[10] = s12; fv[11] = s22;

    float det = f[0] * (f[4] * f[8] - f[5] * f[7])
              - f[1] * (f[3] * f[8] - f[5] * f[6])
              + f[2] * (f[3] * f[7] - f[4] * f[6]);
    float detc = det < 0.0f ? 1e-9f : det;
    fv[12] = detc;
    fv[13] = __builtin_amdgcn_logf(detc) * 0.6931471805599453f;
    float f00c = fmaxf(f[0], 1e-6f);
    fv[14] = f00c;
    fv[15] = __builtin_amdgcn_logf(f00c) * 0.6931471805599453f;

    // Jacobi eigendecomposition of FtF (round-1/2-verified algorithm)
    float a00 = s00, a01 = s01, a02 = s02, a11 = s11, a12 = s12, a22 = s22;
    float v00 = 1.f, v01 = 0.f, v02 = 0.f;
    float v10 = 0.f, v11 = 1.f, v12 = 0.f;
    float v20 = 0.f, v21 = 0.f, v22 = 1.f;
    auto rot = [](float& app, float& aqq, float& apq, float& arp, float& arq,
                  float& Vp0, float& Vq0, float& Vp1, float& Vq1, float& Vp2, float& Vq2) {
        float pq = apq;
        if (fabsf(pq) > 1e-20f) {
            float tau = (aqq - app) * 0.5f * __builtin_amdgcn_rcpf(pq);
            float tt = copysignf(__builtin_amdgcn_rcpf(
                           fabsf(tau) + __builtin_amdgcn_sqrtf(fmaf(tau, tau, 1.0f))), tau);
            float cc = __builtin_amdgcn_rsqf(fmaf(tt, tt, 1.0f));
            float ss = tt * cc;
            app = app - tt * pq;  aqq = aqq + tt * pq;  apq = 0.0f;
            float rp = arp, rq = arq;
            arp = cc * rp - ss * rq;  arq = ss * rp + cc * rq;
            float x0 = Vp0, y0 = Vq0; Vp0 = cc * x0 - ss * y0; Vq0 = ss * x0 + cc * y0;
            float x1 = Vp1, y1 = Vq1; Vp1 = cc * x1 - ss * y1; Vq1 = ss * x1 + cc * y1;
            float x2 = Vp2, y2 = Vq2; Vp2 = cc * x2 - ss * y2; Vq2 = ss * x2 + cc * y2;
        }
    };
    #pragma unroll
    for (int sweep = 0; sweep < 4; ++sweep) {
        rot(a00, a11, a01, a02, a12, v00, v01, v10, v11, v20, v21);
        rot(a00, a22, a02, a01, a12, v00, v02, v10, v12, v20, v22);
        rot(a11, a22, a12, a01, a02, v01, v02, v11, v12, v21, v22);
    }
    #define CSWAP(La, Lb, pA0, pB0, pA1, pB1, pA2, pB2)                     \
        if (La < Lb) { float t_;                                            \
            t_ = La; La = Lb; Lb = t_;   t_ = pA0; pA0 = pB0; pB0 = t_;     \
            t_ = pA1; pA1 = pB1; pB1 = t_; t_ = pA2; pA2 = pB2; pB2 = t_; }
    CSWAP(a00, a11, v00, v01, v10, v11, v20, v21)
    CSWAP(a00, a22, v00, v02, v10, v12, v20, v22)
    CSWAP(a11, a22, v01, v02, v11, v12, v21, v22)
    #undef CSWAP

    float sg0 = __builtin_amdgcn_sqrtf(fmaxf(a00, 0.0f));
    float sg1 = __builtin_amdgcn_sqrtf(fmaxf(a11, 0.0f));
    float sg2 = __builtin_amdgcn_sqrtf(fmaxf(a22, 0.0f));
    fv[0] = sg0; fv[1] = sg1; fv[2] = sg2;

    float i0 = __builtin_amdgcn_rcpf(fmaxf(sg0, 1e-12f));
    float i1 = __builtin_amdgcn_rcpf(fmaxf(sg1, 1e-12f));
    float i2 = __builtin_amdgcn_rcpf(fmaxf(sg2, 1e-12f));
    float A00 = i0*v00*v00 + i1*v01*v01 + i2*v02*v02;
    float A01 = i0*v00*v10 + i1*v01*v11 + i2*v02*v12;
    float A02 = i0*v00*v20 + i1*v01*v21 + i2*v02*v22;
    float A11 = i0*v10*v10 + i1*v11*v11 + i2*v12*v12;
    float A12 = i0*v10*v20 + i1*v11*v21 + i2*v12*v22;
    float A22 = i0*v20*v20 + i1*v21*v21 + i2*v22*v22;
    float R00 = f[0]*A00 + f[1]*A01 + f[2]*A02;
    float R01 = f[0]*A01 + f[1]*A11 + f[2]*A12;
    float R02 = f[0]*A02 + f[1]*A12 + f[2]*A22;
    float R10 = f[3]*A00 + f[4]*A01 + f[5]*A02;
    float R11 = f[3]*A01 + f[4]*A11 + f[5]*A12;
    float R12 = f[3]*A02 + f[4]*A12 + f[5]*A22;
    float R20 = f[6]*A00 + f[7]*A01 + f[8]*A02;
    float R21 = f[6]*A01 + f[7]*A11 + f[8]*A12;
    float R22 = f[6]*A02 + f[7]*A12 + f[8]*A22;

    // feature row: each wave writes its half (units wv*8 .. wv*8+7)
    #pragma unroll
    for (int u = 0; u < 8; ++u) {
        const int uu = wv * 8 + u;
        f32x4 p = { fv[4*uu], fv[4*uu+1], fv[4*uu+2], fv[4*uu+3] };
        *(f32x4*)hu(hrow, swz, uu) = p;
    }
    __syncthreads();                              // features visible

    // ================= MLP: 4 x (64->64, gelu), split across waves =========
    mlp_layer<14, true >(hrow, swz, wvu, w1, b1); // K=57
    mlp_layer<16, false>(hrow, swz, wvu, w2, b2);
    mlp_layer<16, false>(hrow, swz, wvu, w3, b3);
    mlp_layer<16, false>(hrow, swz, wvu, w4, b4);

    // ================= head: 64 -> 9, k-split across waves =================
    // wave wv sums k in [wv*32, wv*32+32) (units wv*8..+7, its own gelu half
    // is already local-read-safe). wave1 parks its partial in units 8..10 of
    // the row (disjoint from wave0's reads, same-wave order for its own).
    f32x2 o01, o23, o45, o67; float o8;
    if (wvu == 0) {
        o01 = { b5[0], b5[1] }; o23 = { b5[2], b5[3] };
        o45 = { b5[4], b5[5] }; o67 = { b5[6], b5[7] }; o8 = b5[8];
    } else {
        o01 = { 0.f, 0.f }; o23 = { 0.f, 0.f };
        o45 = { 0.f, 0.f }; o67 = { 0.f, 0.f }; o8 = 0.f;
    }
    #pragma clang loop unroll_count(2)
    for (int u = 0; u < 8; ++u) {
        f32x4 hv = *(const f32x4*)hu(hrow, swz, wvu * 8 + u);
        #pragma unroll
        for (int j = 0; j < 4; ++j) {
            const float hk = hv[j];
            const f32x2 hk2 = { hk, hk };
            const float* wr = w5 + (wvu * 32 + u * 4 + j) * 9;
            f32x2 w01 = { wr[0], wr[1] }, w23 = { wr[2], wr[3] };
            f32x2 w45 = { wr[4], wr[5] }, w67 = { wr[6], wr[7] };
            o01 = __builtin_elementwise_fma(hk2, w01, o01);
            o23 = __builtin_elementwise_fma(hk2, w23, o23);
            o45 = __builtin_elementwise_fma(hk2, w45, o45);
            o67 = __builtin_elementwise_fma(hk2, w67, o67);
            o8  = fmaf(hk, wr[8], o8);
        }
    }
    if (wv == 1) {
        f32x4 p0 = { o01[0], o01[1], o23[0], o23[1] };
        f32x4 p1 = { o45[0], o45[1], o67[0], o67[1] };
        f32x4 p2 = { o8, 0.f, 0.f, 0.f };
        *(f32x4*)hu(hrow, swz, 8)  = p0;
        *(f32x4*)hu(hrow, swz, 9)  = p1;
        *(f32x4*)hu(hrow, swz, 10) = p2;
    }
    __syncthreads();                              // partials visible

    if (wv != 0 || !live) return;

    f32x4 p0 = *(const f32x4*)hu(hrow, swz, 8);
    f32x4 p1 = *(const f32x4*)hu(hrow, swz, 9);
    f32x4 p2 = *(const f32x4*)hu(hrow, swz, 10);
    float o[9] = { o01[0] + p0[0], o01[1] + p0[1], o23[0] + p0[2], o23[1] + p0[3],
                   o45[0] + p1[0], o45[1] + p1[1], o67[0] + p1[2], o67[1] + p1[3],
                   o8 + p2[0] };

    // ================= epilogue: symmetrize, P = R*xs, cauchy = P*F^T ======
    float xs00 = o[0];
    float xs01 = 0.5f * (o[1] + o[3]);
    float xs02 = 0.5f * (o[2] + o[6]);
    float xs11 = o[4];
    float xs12 = 0.5f * (o[5] + o[7]);
    float xs22 = o[8];

    float P00 = R00*xs00 + R01*xs01 + R02*xs02;
    float P01 = R00*xs01 + R01*xs11 + R02*xs12;
    float P02 = R00*xs02 + R01*xs12 + R02*xs22;
    float P10 = R10*xs00 + R11*xs01 + R12*xs02;
    float P11 = R10*xs01 + R11*xs11 + R12*xs12;
    float P12 = R10*xs02 + R11*xs12 + R12*xs22;
    float P20 = R20*xs00 + R21*xs01 + R22*xs02;
    float P21 = R20*xs01 + R21*xs11 + R22*xs12;
    float P22 = R20*xs02 + R21*xs12 + R22*xs22;

    // cauchy[i][j] = sum_k P[i][k] * F[j][k]
    // NOTE: op[7] = P20*f[3] + P21*f[4] + P22*f[5] (f[5], not f[7]).
    float* op = out + b * 9;
    op[0] = P00*f[0] + P01*f[1] + P02*f[2];
    op[1] = P00*f[3] + P01*f[4] + P02*f[5];
    op[2] = P00*f[6] + P01*f[7] + P02*f[8];
    op[3] = P10*f[0] + P11*f[1] + P12*f[2];
    op[4] = P10*f[3] + P11*f[4] + P12*f[5];
    op[5] = P10*f[6] + P11*f[7] + P12*f[8];
    op[6] = P20*f[0] + P21*f[1] + P22*f[2];
    op[7] = P20*f[3] + P21*f[4] + P22*f[5];
    op[8] = P20*f[6] + P21*f[7] + P22*f[8];
}

extern "C" void kernel_launch(void* const* d_in, const int* in_sizes, int n_in,
                              void* d_out, int out_size, void* d_ws, size_t ws_size,
                              hipStream_t stream) {
    const float* F     = (const float*)d_in[0];
    const float* C     = (const float*)d_in[1];
    const float* w1    = (const float*)d_in[2];
    const float* b1    = (const float*)d_in[3];
    const float* w2    = (const float*)d_in[4];
    const float* b2    = (const float*)d_in[5];
    const float* w3    = (const float*)d_in[6];
    const float* b3    = (const float*)d_in[7];
    const float* w4    = (const float*)d_in[8];
    const float* b4    = (const float*)d_in[9];
    const float* w5    = (const float*)d_in[10];
    const float* b5    = (const float*)d_in[11];
    const float* trajw = (const float*)d_in[12];
    const int*   tids  = (const int*)d_in[13];
    float* out = (float*)d_out;
    (void)d_ws; (void)ws_size;

    int B = in_sizes[0] / 9;
    int grid = (B + 63) / 64;
    stress_main<<<grid, 128, 0, stream>>>(F, C, trajw, tids,
                                          w1, b1, w2, b2, w3, b3, w4, b4, w5, b5,
                                          out, B);
}

// Round 10
// 563.334 us; speedup vs baseline: 1.4513x; 1.0794x over previous
//
#include <hip/hip_runtime.h>
#include <math.h>

typedef float f32x2 __attribute__((ext_vector_type(2)));
typedef float f32x4 __attribute__((ext_vector_type(4)));

// gelu exact-form via A&S 7.1.26 erf (|eps|<=1.5e-7); rcp/exp2 single-instr.
__device__ __forceinline__ float gelu(float x) {
    float z  = x * 0.70710678118654752f;
    float az = fabsf(z);
    float t  = __builtin_amdgcn_rcpf(fmaf(0.3275911f, az, 1.0f));
    float poly = fmaf(fmaf(fmaf(fmaf(1.061405429f, t, -1.453152027f), t,
                       1.421413741f), t, -0.284496736f), t, 0.254829592f);
    float e  = __builtin_amdgcn_exp2f(az * az * -1.4426950408889634f);
    float erfa = fmaf(-poly * t, e, 1.0f);
    float erfz = copysignf(erfa, z);
    return 0.5f * x * (1.0f + erfz);
}

// h row: one per SAMPLE (64 fp32 = 16 x 16B units), shared by the block's two
// waves. Unit index XOR-swizzled by (sample&15): rows are 256B (bank-aligned),
// so unswizzled all lanes would hit one 4-bank group; the XOR spreads 64 lanes
// across 8 groups -> 8 accesses/bank = the b128 minimum (conflict-free).
__device__ __forceinline__ float* hu(float* hrow, int swz, int u) {
    return hrow + ((u ^ swz) << 2);
}

// One MLP layer: this thread computes out[n], n in [wvu*32, wvu*32+32), for
// its sample, summing over ALL k (reads the full row). Weight/bias addresses
// are wave-uniform (wvu from readfirstlane) -> scalar s_load broadcast.
// Cross-wave RAW/WAR on the row handled by the two barriers.
template <int NFULL, bool TAIL>
__device__ __forceinline__ void mlp_layer(float* hrow, int swz, int wvu, int wv,
                                          const float* __restrict__ W,
                                          const float* __restrict__ bias) {
    f32x2 acc[16];
    const float* bh = bias + wvu * 32;
    #pragma unroll
    for (int m = 0; m < 16; ++m)
        acc[m] = *(const f32x2*)(bh + 2 * m);

    #pragma clang loop unroll_count(2)
    for (int u = 0; u < NFULL; ++u) {
        f32x4 hv = *(const f32x4*)hu(hrow, swz, u);
        #pragma unroll
        for (int j = 0; j < 4; ++j) {
            const float hk = hv[j];
            const f32x2 hk2 = { hk, hk };
            const f32x2* wr = (const f32x2*)(W + (u * 4 + j) * 64 + wvu * 32);
            #pragma unroll
            for (int m = 0; m < 16; ++m)
                acc[m] = __builtin_elementwise_fma(hk2, wr[m], acc[m]);
        }
    }
    if constexpr (TAIL) {                 // layer 1: k = 56 only (57..63 unused)
        f32x4 hv = *(const f32x4*)hu(hrow, swz, NFULL);
        const f32x2 hk2 = { hv[0], hv[0] };
        const f32x2* wr = (const f32x2*)(W + (NFULL * 4) * 64 + wvu * 32);
        #pragma unroll
        for (int m = 0; m < 16; ++m)
            acc[m] = __builtin_elementwise_fma(hk2, wr[m], acc[m]);
    }

    __syncthreads();                      // all reads of old h done (block-wide)
    #pragma unroll
    for (int u = 0; u < 8; ++u) {
        f32x4 g;
        g[0] = gelu(acc[2 * u][0]);     g[1] = gelu(acc[2 * u][1]);
        g[2] = gelu(acc[2 * u + 1][0]); g[3] = gelu(acc[2 * u + 1][1]);
        *(f32x4*)hu(hrow, swz, wv * 8 + u) = g;   // own n-half: units wv*8..+7
    }
    __syncthreads();                      // new h visible to both waves
}

// ---------- single kernel: features + polar + fp32 MLP + epilogue ----------
// Block = 128 threads = 2 waves over 64 samples; wave wv owns n-half wv.
// No min-waves clamp: round 9's (128,4) forced VGPR=44 + ~525MB scratch spill
// (WRITE_SIZE 561MB). Natural allocation (~70-85 VGPR) + 16KB LDS gives
// 4.5-6 waves/SIMD spill-free.
__global__ void __launch_bounds__(128) stress_main(
    const float* __restrict__ F, const float* __restrict__ Cin,
    const float* __restrict__ trajw, const int* __restrict__ traj_ids,
    const float* __restrict__ w1, const float* __restrict__ b1,
    const float* __restrict__ w2, const float* __restrict__ b2,
    const float* __restrict__ w3, const float* __restrict__ b3,
    const float* __restrict__ w4, const float* __restrict__ b4,
    const float* __restrict__ w5, const float* __restrict__ b5,
    float* __restrict__ out, int Btotal)
{
    __shared__ float hbuf[64 * 64];               // 16,384 B
    const int t    = threadIdx.x;
    const int lane = t & 63;                      // sample within block
    const int wv   = t >> 6;                      // n-half
    const int wvu  = __builtin_amdgcn_readfirstlane(wv);  // SGPR (scalar W loads)
    const int swz  = lane & 15;
    const int b    = blockIdx.x * 64 + lane;
    const bool live = (b < Btotal);
    float* hrow = hbuf + lane * 64;
    // per-element feature write into the swizzled row (one-time, prologue only)
    auto hset = [&](int k, float v) {
        hrow[(((k >> 2) ^ swz) << 2) | (k & 3)] = v;
    };

    // ================= prologue: features + polar decomposition ============
    // Wave 0: full feature/Jacobi path, writes k0..31, keeps R/f for epilogue.
    // Wave 1: only the latent half (k32..56) - no duplicated Jacobi.
    // No fv[] array: every feature goes straight to LDS (kills the VGPR hog
    // that spilled under round 9's launch_bounds clamp).
    float f[9];
    float R00=0,R01=0,R02=0,R10=0,R11=0,R12=0,R20=0,R21=0,R22=0;
    const int tid0 = traj_ids[0];
    const float* lp = trajw + tid0 * 32;

    if (wvu == 0) {
        if (live) {
            const float* Fp = F + b * 9;
            #pragma unroll
            for (int i = 0; i < 9; ++i) f[i] = Fp[i];
            const float* Cp = Cin + b * 9;
            #pragma unroll
            for (int i = 0; i < 9; ++i) hset(16 + i, Cp[i]);
        } else {
            #pragma unroll
            for (int i = 0; i < 9; ++i) { f[i] = 0.0f; hset(16 + i, 0.0f); }
        }
        #pragma unroll
        for (int e = 0; e < 7; ++e) hset(25 + e, lp[e]);

        float s00 = fmaf(f[0], f[0], fmaf(f[3], f[3], f[6] * f[6]));
        float s01 = fmaf(f[0], f[1], fmaf(f[3], f[4], f[6] * f[7]));
        float s02 = fmaf(f[0], f[2], fmaf(f[3], f[5], f[6] * f[8]));
        float s11 = fmaf(f[1], f[1], fmaf(f[4], f[4], f[7] * f[7]));
        float s12 = fmaf(f[1], f[2], fmaf(f[4], f[5], f[7] * f[8]));
        float s22 = fmaf(f[2], f[2], fmaf(f[5], f[5], f[8] * f[8]));
        hset(3, s00); hset(4, s01); hset(5, s02);
        hset(6, s01); hset(7, s11); hset(8, s12);
        hset(9, s02); hset(10, s12); hset(11, s22);

        float det = f[0] * (f[4] * f[8] - f[5] * f[7])
                  - f[1] * (f[3] * f[8] - f[5] * f[6])
                  + f[2] * (f[3] * f[7] - f[4] * f[6]);
        float detc = det < 0.0f ? 1e-9f : det;
        hset(12, detc);
        hset(13, __builtin_amdgcn_logf(detc) * 0.6931471805599453f);
        float f00c = fmaxf(f[0], 1e-6f);
        hset(14, f00c);
        hset(15, __builtin_amdgcn_logf(f00c) * 0.6931471805599453f);

        // Jacobi eigendecomposition of FtF (round-1/2-verified algorithm)
        float a00 = s00, a01 = s01, a02 = s02, a11 = s11, a12 = s12, a22 = s22;
        float v00 = 1.f, v01 = 0.f, v02 = 0.f;
        float v10 = 0.f, v11 = 1.f, v12 = 0.f;
        float v20 = 0.f, v21 = 0.f, v22 = 1.f;
        auto rot = [](float& app, float& aqq, float& apq, float& arp, float& arq,
                      float& Vp0, float& Vq0, float& Vp1, float& Vq1, float& Vp2, float& Vq2) {
            float pq = apq;
            if (fabsf(pq) > 1e-20f) {
                float tau = (aqq - app) * 0.5f * __builtin_amdgcn_rcpf(pq);
                float tt = copysignf(__builtin_amdgcn_rcpf(
                               fabsf(tau) + __builtin_amdgcn_sqrtf(fmaf(tau, tau, 1.0f))), tau);
                float cc = __builtin_amdgcn_rsqf(fmaf(tt, tt, 1.0f));
                float ss = tt * cc;
                app = app - tt * pq;  aqq = aqq + tt * pq;  apq = 0.0f;
                float rp = arp, rq = arq;
                arp = cc * rp - ss * rq;  arq = ss * rp + cc * rq;
                float x0 = Vp0, y0 = Vq0; Vp0 = cc * x0 - ss * y0; Vq0 = ss * x0 + cc * y0;
                float x1 = Vp1, y1 = Vq1; Vp1 = cc * x1 - ss * y1; Vq1 = ss * x1 + cc * y1;
                float x2 = Vp2, y2 = Vq2; Vp2 = cc * x2 - ss * y2; Vq2 = ss * x2 + cc * y2;
            }
        };
        #pragma unroll
        for (int sweep = 0; sweep < 4; ++sweep) {
            rot(a00, a11, a01, a02, a12, v00, v01, v10, v11, v20, v21);
            rot(a00, a22, a02, a01, a12, v00, v02, v10, v12, v20, v22);
            rot(a11, a22, a12, a01, a02, v01, v02, v11, v12, v21, v22);
        }
        #define CSWAP(La, Lb, pA0, pB0, pA1, pB1, pA2, pB2)                     \
            if (La < Lb) { float t_;                                            \
                t_ = La; La = Lb; Lb = t_;   t_ = pA0; pA0 = pB0; pB0 = t_;     \
                t_ = pA1; pA1 = pB1; pB1 = t_; t_ = pA2; pA2 = pB2; pB2 = t_; }
        CSWAP(a00, a11, v00, v01, v10, v11, v20, v21)
        CSWAP(a00, a22, v00, v02, v10, v12, v20, v22)
        CSWAP(a11, a22, v01, v02, v11, v12, v21, v22)
        #undef CSWAP

        float sg0 = __builtin_amdgcn_sqrtf(fmaxf(a00, 0.0f));
        float sg1 = __builtin_amdgcn_sqrtf(fmaxf(a11, 0.0f));
        float sg2 = __builtin_amdgcn_sqrtf(fmaxf(a22, 0.0f));
        hset(0, sg0); hset(1, sg1); hset(2, sg2);

        float i0 = __builtin_amdgcn_rcpf(fmaxf(sg0, 1e-12f));
        float i1 = __builtin_amdgcn_rcpf(fmaxf(sg1, 1e-12f));
        float i2 = __builtin_amdgcn_rcpf(fmaxf(sg2, 1e-12f));
        float A00 = i0*v00*v00 + i1*v01*v01 + i2*v02*v02;
        float A01 = i0*v00*v10 + i1*v01*v11 + i2*v02*v12;
        float A02 = i0*v00*v20 + i1*v01*v21 + i2*v02*v22;
        float A11 = i0*v10*v10 + i1*v11*v11 + i2*v12*v12;
        float A12 = i0*v10*v20 + i1*v11*v21 + i2*v12*v22;
        float A22 = i0*v20*v20 + i1*v21*v21 + i2*v22*v22;
        R00 = f[0]*A00 + f[1]*A01 + f[2]*A02;
        R01 = f[0]*A01 + f[1]*A11 + f[2]*A12;
        R02 = f[0]*A02 + f[1]*A12 + f[2]*A22;
        R10 = f[3]*A00 + f[4]*A01 + f[5]*A02;
        R11 = f[3]*A01 + f[4]*A11 + f[5]*A12;
        R12 = f[3]*A02 + f[4]*A12 + f[5]*A22;
        R20 = f[6]*A00 + f[7]*A01 + f[8]*A02;
        R21 = f[6]*A01 + f[7]*A11 + f[8]*A12;
        R22 = f[6]*A02 + f[7]*A12 + f[8]*A22;
    } else {
        #pragma unroll
        for (int i = 0; i < 9; ++i) f[i] = 0.0f;
        #pragma unroll
        for (int e = 7; e < 32; ++e) hset(25 + e, lp[e]);   // k32..56
    }
    __syncthreads();                              // features visible

    // ================= MLP: 4 x (64->64, gelu), split across waves =========
    mlp_layer<14, true >(hrow, swz, wvu, wv, w1, b1); // K=57
    mlp_layer<16, false>(hrow, swz, wvu, wv, w2, b2);
    mlp_layer<16, false>(hrow, swz, wvu, wv, w3, b3);
    mlp_layer<16, false>(hrow, swz, wvu, wv, w4, b4);

    // ================= head: 64 -> 9, k-split across waves =================
    // wave wv sums k in [wv*32, wv*32+32) (its own gelu half, same-thread).
    // wave1 parks its partial in units 8..10 (WAR same-thread, then barrier).
    f32x2 o01, o23, o45, o67; float o8;
    if (wvu == 0) {
        o01 = { b5[0], b5[1] }; o23 = { b5[2], b5[3] };
        o45 = { b5[4], b5[5] }; o67 = { b5[6], b5[7] }; o8 = b5[8];
    } else {
        o01 = { 0.f, 0.f }; o23 = { 0.f, 0.f };
        o45 = { 0.f, 0.f }; o67 = { 0.f, 0.f }; o8 = 0.f;
    }
    #pragma clang loop unroll_count(2)
    for (int u = 0; u < 8; ++u) {
        f32x4 hv = *(const f32x4*)hu(hrow, swz, wvu * 8 + u);
        #pragma unroll
        for (int j = 0; j < 4; ++j) {
            const float hk = hv[j];
            const f32x2 hk2 = { hk, hk };
            const float* wr = w5 + (wvu * 32 + u * 4 + j) * 9;
            f32x2 w01 = { wr[0], wr[1] }, w23 = { wr[2], wr[3] };
            f32x2 w45 = { wr[4], wr[5] }, w67 = { wr[6], wr[7] };
            o01 = __builtin_elementwise_fma(hk2, w01, o01);
            o23 = __builtin_elementwise_fma(hk2, w23, o23);
            o45 = __builtin_elementwise_fma(hk2, w45, o45);
            o67 = __builtin_elementwise_fma(hk2, w67, o67);
            o8  = fmaf(hk, wr[8], o8);
        }
    }
    if (wv == 1) {
        f32x4 p0 = { o01[0], o01[1], o23[0], o23[1] };
        f32x4 p1 = { o45[0], o45[1], o67[0], o67[1] };
        f32x4 p2 = { o8, 0.f, 0.f, 0.f };
        *(f32x4*)hu(hrow, swz, 8)  = p0;
        *(f32x4*)hu(hrow, swz, 9)  = p1;
        *(f32x4*)hu(hrow, swz, 10) = p2;
    }
    __syncthreads();                              // partials visible

    if (wv != 0 || !live) return;

    f32x4 p0 = *(const f32x4*)hu(hrow, swz, 8);
    f32x4 p1 = *(const f32x4*)hu(hrow, swz, 9);
    f32x4 p2 = *(const f32x4*)hu(hrow, swz, 10);
    float o[9] = { o01[0] + p0[0], o01[1] + p0[1], o23[0] + p0[2], o23[1] + p0[3],
                   o45[0] + p1[0], o45[1] + p1[1], o67[0] + p1[2], o67[1] + p1[3],
                   o8 + p2[0] };

    // ================= epilogue: symmetrize, P = R*xs, cauchy = P*F^T ======
    float xs00 = o[0];
    float xs01 = 0.5f * (o[1] + o[3]);
    float xs02 = 0.5f * (o[2] + o[6]);
    float xs11 = o[4];
    float xs12 = 0.5f * (o[5] + o[7]);
    float xs22 = o[8];

    float P00 = R00*xs00 + R01*xs01 + R02*xs02;
    float P01 = R00*xs01 + R01*xs11 + R02*xs12;
    float P02 = R00*xs02 + R01*xs12 + R02*xs22;
    float P10 = R10*xs00 + R11*xs01 + R12*xs02;
    float P11 = R10*xs01 + R11*xs11 + R12*xs12;
    float P12 = R10*xs02 + R11*xs12 + R12*xs22;
    float P20 = R20*xs00 + R21*xs01 + R22*xs02;
    float P21 = R20*xs01 + R21*xs11 + R22*xs12;
    float P22 = R20*xs01*0.0f + R20*xs02 + R21*xs12 + R22*xs22; // see below

    // (kept explicit to avoid typo regression; P22 recomputed cleanly)
    P22 = R20*xs02 + R21*xs12 + R22*xs22;

    // cauchy[i][j] = sum_k P[i][k] * F[j][k]
    // NOTE: op[7] = P20*f[3] + P21*f[4] + P22*f[5] (f[5], not f[7]).
    float* op = out + b * 9;
    op[0] = P00*f[0] + P01*f[1] + P02*f[2];
    op[1] = P00*f[3] + P01*f[4] + P02*f[5];
    op[2] = P00*f[6] + P01*f[7] + P02*f[8];
    op[3] = P10*f[0] + P11*f[1] + P12*f[2];
    op[4] = P10*f[3] + P11*f[4] + P12*f[5];
    op[5] = P10*f[6] + P11*f[7] + P12*f[8];
    op[6] = P20*f[0] + P21*f[1] + P22*f[2];
    op[7] = P20*f[3] + P21*f[4] + P22*f[5];
    op[8] = P20*f[6] + P21*f[7] + P22*f[8];
}

extern "C" void kernel_launch(void* const* d_in, const int* in_sizes, int n_in,
                              void* d_out, int out_size, void* d_ws, size_t ws_size,
                              hipStream_t stream) {
    const float* F     = (const float*)d_in[0];
    const float* C     = (const float*)d_in[1];
    const float* w1    = (const float*)d_in[2];
    const float* b1    = (const float*)d_in[3];
    const float* w2    = (const float*)d_in[4];
    const float* b2    = (const float*)d_in[5];
    const float* w3    = (const float*)d_in[6];
    const float* b3    = (const float*)d_in[7];
    const float* w4    = (const float*)d_in[8];
    const float* b4    = (const float*)d_in[9];
    const float* w5    = (const float*)d_in[10];
    const float* b5    = (const float*)d_in[11];
    const float* trajw = (const float*)d_in[12];
    const int*   tids  = (const int*)d_in[13];
    float* out = (float*)d_out;
    (void)d_ws; (void)ws_size;

    int B = in_sizes[0] / 9;
    int grid = (B + 63) / 64;
    stress_main<<<grid, 128, 0, stream>>>(F, C, trajw, tids,
                                          w1, b1, w2, b2, w3, b3, w4, b4, w5, b5,
                                          out, B);
}

// Round 11
// 517.097 us; speedup vs baseline: 1.5810x; 1.0894x over previous
//
#include <hip/hip_runtime.h>
#include <math.h>

typedef float f32x2 __attribute__((ext_vector_type(2)));
typedef float f32x4 __attribute__((ext_vector_type(4)));

// gelu exact-form via A&S 7.1.26 erf (|eps|<=1.5e-7); rcp/exp2 single-instr.
__device__ __forceinline__ float gelu(float x) {
    float z  = x * 0.70710678118654752f;
    float az = fabsf(z);
    float t  = __builtin_amdgcn_rcpf(fmaf(0.3275911f, az, 1.0f));
    float poly = fmaf(fmaf(fmaf(fmaf(1.061405429f, t, -1.453152027f), t,
                       1.421413741f), t, -0.284496736f), t, 0.254829592f);
    float e  = __builtin_amdgcn_exp2f(az * az * -1.4426950408889634f);
    float erfa = fmaf(-poly * t, e, 1.0f);
    float erfz = copysignf(erfa, z);
    return 0.5f * x * (1.0f + erfz);
}

// h row: one per SAMPLE (64 fp32 = 16 x 16B units), shared by the block's 4
// waves. Unit index XOR-swizzled by (sample&15): rows are 256B (bank-aligned);
// the XOR spreads 64 lanes' b128 accesses to 8/bank = the b128 minimum.
__device__ __forceinline__ float* hu(float* hrow, int swz, int u) {
    return hrow + ((u ^ swz) << 2);
}

// One MLP layer: this thread computes out[n], n in [wvu*16, wvu*16+16), for
// its sample, summing over all K k-values (reads the row). Weight/bias
// addresses wave-uniform (wvu = readfirstlane) -> scalar s_load broadcast.
// Cross-wave RAW/WAR on the row handled by the two barriers.
template <int NFULL, bool TAIL>
__device__ __forceinline__ void mlp_layer(float* hrow, int swz, int wvu, int wv,
                                          const float* __restrict__ W,
                                          const float* __restrict__ bias) {
    f32x2 acc[8];
    const float* bh = bias + wvu * 16;
    #pragma unroll
    for (int m = 0; m < 8; ++m)
        acc[m] = *(const f32x2*)(bh + 2 * m);

    #pragma clang loop unroll_count(2)
    for (int u = 0; u < NFULL; ++u) {
        f32x4 hv = *(const f32x4*)hu(hrow, swz, u);
        #pragma unroll
        for (int j = 0; j < 4; ++j) {
            const float hk = hv[j];
            const f32x2 hk2 = { hk, hk };
            const f32x2* wr = (const f32x2*)(W + (u * 4 + j) * 64 + wvu * 16);
            #pragma unroll
            for (int m = 0; m < 8; ++m)
                acc[m] = __builtin_elementwise_fma(hk2, wr[m], acc[m]);
        }
    }
    if constexpr (TAIL) {                 // layer 1: k = NFULL*4 (=24) only
        f32x4 hv = *(const f32x4*)hu(hrow, swz, NFULL);
        const f32x2 hk2 = { hv[0], hv[0] };
        const f32x2* wr = (const f32x2*)(W + (NFULL * 4) * 64 + wvu * 16);
        #pragma unroll
        for (int m = 0; m < 8; ++m)
            acc[m] = __builtin_elementwise_fma(hk2, wr[m], acc[m]);
    }

    __syncthreads();                      // all reads of old h done (block-wide)
    #pragma unroll
    for (int u = 0; u < 4; ++u) {
        f32x4 g;
        g[0] = gelu(acc[2 * u][0]);     g[1] = gelu(acc[2 * u][1]);
        g[2] = gelu(acc[2 * u + 1][0]); g[3] = gelu(acc[2 * u + 1][1]);
        *(f32x4*)hu(hrow, swz, wv * 4 + u) = g;   // own n-quarter: units wv*4..+3
    }
    __syncthreads();                      // new h visible to all waves
}

// ---------- prep: fold constant latent into layer-1 bias ----------
// traj_ids[0] is scalar -> latent (32 feats) identical for all samples:
// b1eff[n] = b1[n] + sum_e latent[e] * w1[(25+e)*64 + n].  K1 drops 57->25.
__global__ void prep_bias(const float* __restrict__ w1, const float* __restrict__ b1,
                          const float* __restrict__ trajw, const int* __restrict__ traj_ids,
                          float* __restrict__ ws)
{
    int n = threadIdx.x;                  // 64 threads
    const float* lp = trajw + traj_ids[0] * 32;
    float acc = b1[n];
    #pragma unroll
    for (int e = 0; e < 32; ++e)
        acc = fmaf(lp[e], w1[(25 + e) * 64 + n], acc);
    ws[n] = acc;
}

// ---------- main kernel: features + polar + fp32 MLP + epilogue ----------
// Block = 256 threads = 4 waves over 64 samples; wave wv owns n-quarter wv.
// LDS 16KB + VGPR<=64 (round-10 measured 44) -> 8 blocks/CU = 32 waves/CU
// (100% of the wave cap; round 10 was stuck at ~15).
__global__ void __launch_bounds__(256) stress_main(
    const float* __restrict__ F, const float* __restrict__ Cin,
    const float* __restrict__ b1eff,
    const float* __restrict__ w1,
    const float* __restrict__ w2, const float* __restrict__ b2,
    const float* __restrict__ w3, const float* __restrict__ b3,
    const float* __restrict__ w4, const float* __restrict__ b4,
    const float* __restrict__ w5, const float* __restrict__ b5,
    float* __restrict__ out, int Btotal)
{
    __shared__ float hbuf[64 * 64];               // 16,384 B
    const int t    = threadIdx.x;
    const int lane = t & 63;                      // sample within block
    const int wv   = t >> 6;                      // n-quarter 0..3
    const int wvu  = __builtin_amdgcn_readfirstlane(wv);  // SGPR (scalar W loads)
    const int swz  = lane & 15;
    const int b    = blockIdx.x * 64 + lane;
    const bool live = (b < Btotal);
    float* hrow = hbuf + lane * 64;
    auto hset = [&](int k, float v) {
        hrow[(((k >> 2) ^ swz) << 2) | (k & 3)] = v;
    };

    // ================= prologue =================
    // wave 0: strain features k0..15 + Jacobi/polar (keeps R,f for epilogue)
    // wave 1: C features k16..24.  waves 2,3: idle until the barrier.
    // latent k25..56 no longer exists (folded into b1eff).
    float f[9];
    float R00=0,R01=0,R02=0,R10=0,R11=0,R12=0,R20=0,R21=0,R22=0;

    if (wvu == 0) {
        if (live) {
            const float* Fp = F + b * 9;
            #pragma unroll
            for (int i = 0; i < 9; ++i) f[i] = Fp[i];
        } else {
            #pragma unroll
            for (int i = 0; i < 9; ++i) f[i] = 0.0f;
        }

        float s00 = fmaf(f[0], f[0], fmaf(f[3], f[3], f[6] * f[6]));
        float s01 = fmaf(f[0], f[1], fmaf(f[3], f[4], f[6] * f[7]));
        float s02 = fmaf(f[0], f[2], fmaf(f[3], f[5], f[6] * f[8]));
        float s11 = fmaf(f[1], f[1], fmaf(f[4], f[4], f[7] * f[7]));
        float s12 = fmaf(f[1], f[2], fmaf(f[4], f[5], f[7] * f[8]));
        float s22 = fmaf(f[2], f[2], fmaf(f[5], f[5], f[8] * f[8]));
        hset(3, s00); hset(4, s01); hset(5, s02);
        hset(6, s01); hset(7, s11); hset(8, s12);
        hset(9, s02); hset(10, s12); hset(11, s22);

        float det = f[0] * (f[4] * f[8] - f[5] * f[7])
                  - f[1] * (f[3] * f[8] - f[5] * f[6])
                  + f[2] * (f[3] * f[7] - f[4] * f[6]);
        float detc = det < 0.0f ? 1e-9f : det;
        hset(12, detc);
        hset(13, __builtin_amdgcn_logf(detc) * 0.6931471805599453f);
        float f00c = fmaxf(f[0], 1e-6f);
        hset(14, f00c);
        hset(15, __builtin_amdgcn_logf(f00c) * 0.6931471805599453f);

        // Jacobi eigendecomposition of FtF (round-1/2-verified algorithm)
        float a00 = s00, a01 = s01, a02 = s02, a11 = s11, a12 = s12, a22 = s22;
        float v00 = 1.f, v01 = 0.f, v02 = 0.f;
        float v10 = 0.f, v11 = 1.f, v12 = 0.f;
        float v20 = 0.f, v21 = 0.f, v22 = 1.f;
        auto rot = [](float& app, float& aqq, float& apq, float& arp, float& arq,
                      float& Vp0, float& Vq0, float& Vp1, float& Vq1, float& Vp2, float& Vq2) {
            float pq = apq;
            if (fabsf(pq) > 1e-20f) {
                float tau = (aqq - app) * 0.5f * __builtin_amdgcn_rcpf(pq);
                float tt = copysignf(__builtin_amdgcn_rcpf(
                               fabsf(tau) + __builtin_amdgcn_sqrtf(fmaf(tau, tau, 1.0f))), tau);
                float cc = __builtin_amdgcn_rsqf(fmaf(tt, tt, 1.0f));
                float ss = tt * cc;
                app = app - tt * pq;  aqq = aqq + tt * pq;  apq = 0.0f;
                float rp = arp, rq = arq;
                arp = cc * rp - ss * rq;  arq = ss * rp + cc * rq;
                float x0 = Vp0, y0 = Vq0; Vp0 = cc * x0 - ss * y0; Vq0 = ss * x0 + cc * y0;
                float x1 = Vp1, y1 = Vq1; Vp1 = cc * x1 - ss * y1; Vq1 = ss * x1 + cc * y1;
                float x2 = Vp2, y2 = Vq2; Vp2 = cc * x2 - ss * y2; Vq2 = ss * x2 + cc * y2;
            }
        };
        #pragma unroll
        for (int sweep = 0; sweep < 4; ++sweep) {
            rot(a00, a11, a01, a02, a12, v00, v01, v10, v11, v20, v21);
            rot(a00, a22, a02, a01, a12, v00, v02, v10, v12, v20, v22);
            rot(a11, a22, a12, a01, a02, v01, v02, v11, v12, v21, v22);
        }
        #define CSWAP(La, Lb, pA0, pB0, pA1, pB1, pA2, pB2)                     \
            if (La < Lb) { float t_;                                            \
                t_ = La; La = Lb; Lb = t_;   t_ = pA0; pA0 = pB0; pB0 = t_;     \
                t_ = pA1; pA1 = pB1; pB1 = t_; t_ = pA2; pA2 = pB2; pB2 = t_; }
        CSWAP(a00, a11, v00, v01, v10, v11, v20, v21)
        CSWAP(a00, a22, v00, v02, v10, v12, v20, v22)
        CSWAP(a11, a22, v01, v02, v11, v12, v21, v22)
        #undef CSWAP

        float sg0 = __builtin_amdgcn_sqrtf(fmaxf(a00, 0.0f));
        float sg1 = __builtin_amdgcn_sqrtf(fmaxf(a11, 0.0f));
        float sg2 = __builtin_amdgcn_sqrtf(fmaxf(a22, 0.0f));
        hset(0, sg0); hset(1, sg1); hset(2, sg2);

        float i0 = __builtin_amdgcn_rcpf(fmaxf(sg0, 1e-12f));
        float i1 = __builtin_amdgcn_rcpf(fmaxf(sg1, 1e-12f));
        float i2 = __builtin_amdgcn_rcpf(fmaxf(sg2, 1e-12f));
        float A00 = i0*v00*v00 + i1*v01*v01 + i2*v02*v02;
        float A01 = i0*v00*v10 + i1*v01*v11 + i2*v02*v12;
        float A02 = i0*v00*v20 + i1*v01*v21 + i2*v02*v22;
        float A11 = i0*v10*v10 + i1*v11*v11 + i2*v12*v12;
        float A12 = i0*v10*v20 + i1*v11*v21 + i2*v12*v22;
        float A22 = i0*v20*v20 + i1*v21*v21 + i2*v22*v22;
        R00 = f[0]*A00 + f[1]*A01 + f[2]*A02;
        R01 = f[0]*A01 + f[1]*A11 + f[2]*A12;
        R02 = f[0]*A02 + f[1]*A12 + f[2]*A22;
        R10 = f[3]*A00 + f[4]*A01 + f[5]*A02;
        R11 = f[3]*A01 + f[4]*A11 + f[5]*A12;
        R12 = f[3]*A02 + f[4]*A12 + f[5]*A22;
        R20 = f[6]*A00 + f[7]*A01 + f[8]*A02;
        R21 = f[6]*A01 + f[7]*A11 + f[8]*A12;
        R22 = f[6]*A02 + f[7]*A12 + f[8]*A22;
    } else if (wvu == 1) {
        #pragma unroll
        for (int i = 0; i < 9; ++i) f[i] = 0.0f;
        if (live) {
            const float* Cp = Cin + b * 9;
            #pragma unroll
            for (int i = 0; i < 9; ++i) hset(16 + i, Cp[i]);
        } else {
            #pragma unroll
            for (int i = 0; i < 9; ++i) hset(16 + i, 0.0f);
        }
    } else {
        #pragma unroll
        for (int i = 0; i < 9; ++i) f[i] = 0.0f;
    }
    __syncthreads();                              // features visible

    // ================= MLP: layer1 K=25 (latent folded), then 3x K=64 ======
    mlp_layer<6,  true >(hrow, swz, wvu, wv, w1, b1eff); // K=25
    mlp_layer<16, false>(hrow, swz, wvu, wv, w2, b2);
    mlp_layer<16, false>(hrow, swz, wvu, wv, w3, b3);
    mlp_layer<16, false>(hrow, swz, wvu, wv, w4, b4);

    // ================= head: 64 -> 9, k-quartered across waves =============
    // wave w sums k in [w*16, w*16+16) (units w*4..+3 = its own gelu quarter,
    // same-thread order). Waves 1..3 park 9-float partials into their own
    // units w*4+{0,1,2} (no other wave reads those during head), barrier,
    // wave 0 merges.
    f32x2 o01, o23, o45, o67; float o8;
    if (wvu == 0) {
        o01 = { b5[0], b5[1] }; o23 = { b5[2], b5[3] };
        o45 = { b5[4], b5[5] }; o67 = { b5[6], b5[7] }; o8 = b5[8];
    } else {
        o01 = { 0.f, 0.f }; o23 = { 0.f, 0.f };
        o45 = { 0.f, 0.f }; o67 = { 0.f, 0.f }; o8 = 0.f;
    }
    #pragma unroll
    for (int u = 0; u < 4; ++u) {
        f32x4 hv = *(const f32x4*)hu(hrow, swz, wvu * 4 + u);
        #pragma unroll
        for (int j = 0; j < 4; ++j) {
            const float hk = hv[j];
            const f32x2 hk2 = { hk, hk };
            const float* wr = w5 + (wvu * 16 + u * 4 + j) * 9;
            f32x2 w01 = { wr[0], wr[1] }, w23 = { wr[2], wr[3] };
            f32x2 w45 = { wr[4], wr[5] }, w67 = { wr[6], wr[7] };
            o01 = __builtin_elementwise_fma(hk2, w01, o01);
            o23 = __builtin_elementwise_fma(hk2, w23, o23);
            o45 = __builtin_elementwise_fma(hk2, w45, o45);
            o67 = __builtin_elementwise_fma(hk2, w67, o67);
            o8  = fmaf(hk, wr[8], o8);
        }
    }
    if (wv != 0) {
        f32x4 p0 = { o01[0], o01[1], o23[0], o23[1] };
        f32x4 p1 = { o45[0], o45[1], o67[0], o67[1] };
        f32x4 p2 = { o8, 0.f, 0.f, 0.f };
        *(f32x4*)hu(hrow, swz, wv * 4 + 0) = p0;
        *(f32x4*)hu(hrow, swz, wv * 4 + 1) = p1;
        *(f32x4*)hu(hrow, swz, wv * 4 + 2) = p2;
    }
    __syncthreads();                              // partials visible

    if (wv != 0 || !live) return;

    float o[9] = { o01[0], o01[1], o23[0], o23[1], o45[0], o45[1], o67[0], o67[1], o8 };
    #pragma unroll
    for (int w = 1; w < 4; ++w) {
        f32x4 p0 = *(const f32x4*)hu(hrow, swz, w * 4 + 0);
        f32x4 p1 = *(const f32x4*)hu(hrow, swz, w * 4 + 1);
        f32x4 p2 = *(const f32x4*)hu(hrow, swz, w * 4 + 2);
        o[0] += p0[0]; o[1] += p0[1]; o[2] += p0[2]; o[3] += p0[3];
        o[4] += p1[0]; o[5] += p1[1]; o[6] += p1[2]; o[7] += p1[3];
        o[8] += p2[0];
    }

    // ================= epilogue: symmetrize, P = R*xs, cauchy = P*F^T ======
    float xs00 = o[0];
    float xs01 = 0.5f * (o[1] + o[3]);
    float xs02 = 0.5f * (o[2] + o[6]);
    float xs11 = o[4];
    float xs12 = 0.5f * (o[5] + o[7]);
    float xs22 = o[8];

    float P00 = R00*xs00 + R01*xs01 + R02*xs02;
    float P01 = R00*xs01 + R01*xs11 + R02*xs12;
    float P02 = R00*xs02 + R01*xs12 + R02*xs22;
    float P10 = R10*xs00 + R11*xs01 + R12*xs02;
    float P11 = R10*xs01 + R11*xs11 + R12*xs12;
    float P12 = R10*xs02 + R11*xs12 + R12*xs22;
    float P20 = R20*xs00 + R21*xs01 + R22*xs02;
    float P21 = R20*xs01 + R21*xs11 + R22*xs12;
    float P22 = R20*xs02 + R21*xs12 + R22*xs22;

    // cauchy[i][j] = sum_k P[i][k] * F[j][k]
    // NOTE: op[7] = P20*f[3] + P21*f[4] + P22*f[5] (f[5], not f[7]).
    float* op = out + b * 9;
    op[0] = P00*f[0] + P01*f[1] + P02*f[2];
    op[1] = P00*f[3] + P01*f[4] + P02*f[5];
    op[2] = P00*f[6] + P01*f[7] + P02*f[8];
    op[3] = P10*f[0] + P11*f[1] + P12*f[2];
    op[4] = P10*f[3] + P11*f[4] + P12*f[5];
    op[5] = P10*f[6] + P11*f[7] + P12*f[8];
    op[6] = P20*f[0] + P21*f[1] + P22*f[2];
    op[7] = P20*f[3] + P21*f[4] + P22*f[5];
    op[8] = P20*f[6] + P21*f[7] + P22*f[8];
}

extern "C" void kernel_launch(void* const* d_in, const int* in_sizes, int n_in,
                              void* d_out, int out_size, void* d_ws, size_t ws_size,
                              hipStream_t stream) {
    const float* F     = (const float*)d_in[0];
    const float* C     = (const float*)d_in[1];
    const float* w1    = (const float*)d_in[2];
    const float* b1    = (const float*)d_in[3];
    const float* w2    = (const float*)d_in[4];
    const float* b2    = (const float*)d_in[5];
    const float* w3    = (const float*)d_in[6];
    const float* b3    = (const float*)d_in[7];
    const float* w4    = (const float*)d_in[8];
    const float* b4    = (const float*)d_in[9];
    const float* w5    = (const float*)d_in[10];
    const float* b5    = (const float*)d_in[11];
    const float* trajw = (const float*)d_in[12];
    const int*   tids  = (const int*)d_in[13];
    float* out = (float*)d_out;
    float* wsf = (float*)d_ws;

    int B = in_sizes[0] / 9;

    prep_bias<<<1, 64, 0, stream>>>(w1, b1, trajw, tids, wsf);

    int grid = (B + 63) / 64;
    stress_main<<<grid, 256, 0, stream>>>(F, C, wsf,
                                          w1, w2, b2, w3, b3, w4, b4, w5, b5,
                                          out, B);
}